// Round 6
// baseline (254.207 us; speedup 1.0000x reference)
//
#include <hip/hip_runtime.h>
#include <hip/hip_bf16.h>

#define NTOK 4096   // 64*64 tokens per batch
#define NPOOL 1024  // 32*32 pooled tokens per batch

using short8 = __attribute__((ext_vector_type(8))) short;
using f32x4  = __attribute__((ext_vector_type(4))) float;

__device__ __forceinline__ unsigned short f2bf(float f) {
  __hip_bfloat16 h = __float2bfloat16(f);
  return __builtin_bit_cast(unsigned short, h);
}

// Map local tile row m (0..63) to a global x row such that rows 4*p..4*p+3 are
// the 2x2 pooling corners of pooled row bx*16+p.
__device__ __forceinline__ int pool_row(int bx, int m) {
  int pg = bx * 16 + (m >> 2);
  int corner = m & 3;
  int batch = pg >> 10;
  int pl = pg & 1023;
  int pi = pl >> 5, pj = pl & 31;
  return (batch << 12) + ((2 * pi + (corner >> 1)) << 6) + 2 * pj + (corner & 1);
}

// Pack weights: wcatT[384][512] = [f(64) | g(64) | h(256)]^T bf16; woT[512][256] bf16.
__global__ __launch_bounds__(256) void pack_w(const float* __restrict__ wf,
                                              const float* __restrict__ wg,
                                              const float* __restrict__ wh,
                                              const float* __restrict__ wo,
                                              unsigned short* __restrict__ wcatT,
                                              unsigned short* __restrict__ woT) {
  int i = blockIdx.x * 256 + threadIdx.x;
  if (i < 384 * 512) {
    int n = i >> 9, k = i & 511;
    float v = (n < 64) ? wf[k * 64 + n]
            : (n < 128) ? wg[k * 64 + (n - 64)]
                        : wh[k * 256 + (n - 128)];
    wcatT[i] = f2bf(v);
  } else if (i < 384 * 512 + 512 * 256) {
    int j = i - 384 * 512;
    int n = j >> 8, k = j & 255;
    woT[j] = f2bf(wo[(size_t)k * 512 + n]);
  }
}

// Fused f/g/h projection, MFMA.
// v4: 512 thr / 8 waves, block tile 64 rows x 384 cols (wave tile 64x48),
// grid 512 (2 blocks/CU). DOUBLE-BUFFERED staging with issue-early/write-late:
// next chunk's global loads issue at chunk top (hidden under MFMA), ds_write
// after compute, ONE barrier per chunk. Prefetch regs = 16 (no spill; R1/R2 lesson).
__global__ __launch_bounds__(512) void fgh_proj(const float* __restrict__ x,
                                                const unsigned short* __restrict__ wcatT,
                                                unsigned short* __restrict__ fB,
                                                unsigned short* __restrict__ gB,
                                                unsigned short* __restrict__ hT) {
  // buf k: As[64][40] @k*17920 ; Ws[384][40] @k*17920+2560  (17920 ush each)
  __shared__ unsigned short lds[35840];
  const int tid = threadIdx.x;
  const int bx = blockIdx.x;
  const int wave = tid >> 6, lane = tid & 63;
  const int col = lane & 15, rgrp = lane >> 4;
  const int wcol = wave * 48;

  // staging maps (constant per thread)
  const int xm = tid >> 3, xk4 = (tid & 7) << 2;
  const float* xsrc = x + (size_t)pool_row(bx, xm) * 512 + xk4;  // + kt*32
  const int xdst = xm * 40 + xk4;
  int wsrc[3], wdst[3];
#pragma unroll
  for (int r = 0; r < 3; ++r) {
    int idx = tid + r * 512;
    int n = idx >> 2, k8 = (idx & 3) << 3;
    wsrc[r] = n * 512 + k8;         // + kt*32
    wdst[r] = 2560 + n * 40 + k8;
  }

  // prologue: chunk 0 -> buf0
  float4 rx = *(const float4*)xsrc;
  uint4 rw[3];
#pragma unroll
  for (int r = 0; r < 3; ++r) rw[r] = *(const uint4*)(wcatT + wsrc[r]);
  {
    ushort4 o4;
    o4.x = f2bf(rx.x); o4.y = f2bf(rx.y); o4.z = f2bf(rx.z); o4.w = f2bf(rx.w);
    *(ushort4*)&lds[xdst] = o4;
  }
#pragma unroll
  for (int r = 0; r < 3; ++r) *(uint4*)&lds[wdst[r]] = rw[r];
  __syncthreads();

  f32x4 acc[4][3];
#pragma unroll
  for (int mt = 0; mt < 4; ++mt)
#pragma unroll
    for (int nt = 0; nt < 3; ++nt) acc[mt][nt] = (f32x4){0.f, 0.f, 0.f, 0.f};

  for (int kt = 0; kt < 16; ++kt) {
    const int cur = (kt & 1) * 17920;
    const int nxt = 17920 - cur;
    if (kt < 15) {  // issue next chunk's loads; latency hides under MFMA below
      rx = *(const float4*)(xsrc + (kt + 1) * 32);
#pragma unroll
      for (int r = 0; r < 3; ++r) rw[r] = *(const uint4*)(wcatT + wsrc[r] + (kt + 1) * 32);
    }

    short8 am[4];
#pragma unroll
    for (int mt = 0; mt < 4; ++mt)
      am[mt] = *(const short8*)&lds[cur + (mt * 16 + col) * 40 + rgrp * 8];
#pragma unroll
    for (int nt = 0; nt < 3; ++nt) {
      short8 bn = *(const short8*)&lds[cur + 2560 + (wcol + nt * 16 + col) * 40 + rgrp * 8];
#pragma unroll
      for (int mt = 0; mt < 4; ++mt)
        acc[mt][nt] = __builtin_amdgcn_mfma_f32_16x16x32_bf16(am[mt], bn, acc[mt][nt], 0, 0, 0);
    }

    if (kt < 15) {  // write-late into the other buffer
      ushort4 o4;
      o4.x = f2bf(rx.x); o4.y = f2bf(rx.y); o4.z = f2bf(rx.z); o4.w = f2bf(rx.w);
      *(ushort4*)&lds[nxt + xdst] = o4;
#pragma unroll
      for (int r = 0; r < 3; ++r) *(uint4*)&lds[nxt + wdst[r]] = rw[r];
    }
    __syncthreads();  // one barrier per chunk
  }

  // epilogue assembly in LDS (alias over buf0; loop-end barrier protects)
  unsigned short* gO = lds;          // [64][72]
  unsigned short* fO = lds + 4608;   // [16][72]
  unsigned short* hO = lds + 5760;   // [256][24]
#pragma unroll
  for (int mt = 0; mt < 4; ++mt) {
#pragma unroll
    for (int nt = 0; nt < 3; ++nt) {
      int n = wcol + nt * 16 + col;
      f32x4 a = acc[mt][nt];
      if (n < 64) {
        float mx = fmaxf(fmaxf(a[0], a[1]), fmaxf(a[2], a[3]));
        fO[(mt * 4 + rgrp) * 72 + n] = f2bf(mx);
      } else if (n < 128) {
#pragma unroll
        for (int reg = 0; reg < 4; ++reg)
          gO[(mt * 16 + rgrp * 4 + reg) * 72 + (n - 64)] = f2bf(a[reg]);
      } else {
        float mx = fmaxf(fmaxf(a[0], a[1]), fmaxf(a[2], a[3]));
        hO[(n - 128) * 24 + (mt * 4 + rgrp)] = f2bf(mx);
      }
    }
  }
  __syncthreads();

  const int b = bx >> 6, pkb = (bx & 63) * 16;
  {  // g: 64 rows x 64 ch (rows permuted), 512 uint4, 1/thread
    int m = tid >> 3, d8 = (tid & 7) << 3;
    *(uint4*)(gB + (size_t)pool_row(bx, m) * 64 + d8) = *(const uint4*)&gO[m * 72 + d8];
  }
  if (tid < 128) {  // f: 16 pooled rows x 64 ch
    int pr = tid >> 3, d8 = (tid & 7) << 3;
    *(uint4*)(fB + (size_t)(bx * 16 + pr) * 64 + d8) = *(const uint4*)&fO[pr * 72 + d8];
  }
  {  // hT: 256 dv x 16 pooled, 512 uint4, 1/thread
    int dv = tid >> 1, p8 = (tid & 1) << 3;
    *(uint4*)(hT + (((size_t)b * 256 + dv) << 10) + pkb + p8) = *(const uint4*)&hO[dv * 24 + p8];
  }
}

// MFMA flash attention; bf16 output o[32768][256].
// v5: 8-wave block, 128 q-rows, 256 blocks (1/CU). DOUBLE-BUFFERED F/H staging,
// issue-early/write-late, ONE barrier per chunk (16+1 vs 32). pS is wave-private
// (each wave writes+reads only its own 16 rows) -> needs no barrier.
// Prefetch regs = 20 on a 76-VGPR base (no spill; R1/R2 lesson).
__global__ __launch_bounds__(512) void attn_mfma(const __hip_bfloat16* __restrict__ G,
                                                 const __hip_bfloat16* __restrict__ F,
                                                 const __hip_bfloat16* __restrict__ HT,
                                                 unsigned short* __restrict__ O) {
  // buf k (k=0,1): fS[64][72] @k*23040 ; hS[256][72] @k*23040+4608   (23040 ush each)
  // pS[128][72] @46080 (9216)
  // epilogue alias: oS[128][264] @0 (33792)
  __shared__ unsigned short lds[55296];  // 110592 B

  const int tid = threadIdx.x;
  const int wave = tid >> 6, lane = tid & 63;
  const int col = lane & 15;
  const int rgrp = lane >> 4;
  const int b = blockIdx.x >> 5, qt = blockIdx.x & 31;

  const unsigned short* Gb = (const unsigned short*)G + ((size_t)b * NTOK + qt * 128) * 64;
  const unsigned short* Fb = (const unsigned short*)F + (size_t)b * NPOOL * 64;
  const unsigned short* Hb = (const unsigned short*)HT + (size_t)b * 256 * NPOOL;

  // Q fragment straight from global (read once)
  short8 ag[2];
#pragma unroll
  for (int ks = 0; ks < 2; ++ks)
    ag[ks] = *(const short8*)(Gb + (size_t)(wave * 16 + col) * 64 + ks * 32 + rgrp * 8);

  // staging maps (constant per thread)
  const int fk = tid >> 3, fd8 = (tid & 7) << 3;
  const int fdst = fk * 72 + fd8;
  const int fsrc = fk * 64 + fd8;              // + kc*4096
  int hdst[4], hsrc[4];
#pragma unroll
  for (int r = 0; r < 4; ++r) {
    int j = tid + r * 512;
    int dv = j >> 3, k8 = (j & 7) << 3;
    hdst[r] = 4608 + dv * 72 + k8;
    hsrc[r] = dv * NPOOL + k8;                 // + kc*64
  }

  // prologue: chunk 0 -> buf0
  uint4 rf = *(const uint4*)(Fb + fsrc);
  uint4 rh[4];
#pragma unroll
  for (int r = 0; r < 4; ++r) rh[r] = *(const uint4*)(Hb + hsrc[r]);
  *(uint4*)&lds[fdst] = rf;
#pragma unroll
  for (int r = 0; r < 4; ++r) *(uint4*)&lds[hdst[r]] = rh[r];
  __syncthreads();

  f32x4 oacc[16];
#pragma unroll
  for (int t = 0; t < 16; ++t) oacc[t] = (f32x4){0.f, 0.f, 0.f, 0.f};
  float m_run[4], l_run[4];
#pragma unroll
  for (int r = 0; r < 4; ++r) { m_run[r] = -1e30f; l_run[r] = 0.f; }

  for (int kc = 0; kc < 16; ++kc) {
    const int cur = (kc & 1) * 23040;
    const int nxt = 23040 - cur;
    if (kc < 15) {  // issue next chunk's loads; latency hides under compute below
      rf = *(const uint4*)(Fb + (kc + 1) * 4096 + fsrc);
#pragma unroll
      for (int r = 0; r < 4; ++r) rh[r] = *(const uint4*)(Hb + (kc + 1) * 64 + hsrc[r]);
    }

    // QK^T
    f32x4 s[4];
#pragma unroll
    for (int t = 0; t < 4; ++t) s[t] = (f32x4){0.f, 0.f, 0.f, 0.f};
#pragma unroll
    for (int ks = 0; ks < 2; ++ks) {
#pragma unroll
      for (int t = 0; t < 4; ++t) {
        short8 bf = *(const short8*)&lds[cur + (t * 16 + col) * 72 + ks * 32 + rgrp * 8];
        s[t] = __builtin_amdgcn_mfma_f32_16x16x32_bf16(ag[ks], bf, s[t], 0, 0, 0);
      }
    }

    // online softmax with exact defer-rescale
    float cm[4];
#pragma unroll
    for (int r = 0; r < 4; ++r) {
      cm[r] = fmaxf(fmaxf(s[0][r], s[1][r]), fmaxf(s[2][r], s[3][r]));
#pragma unroll
      for (int msk = 1; msk < 16; msk <<= 1) cm[r] = fmaxf(cm[r], __shfl_xor(cm[r], msk));
    }
    bool upd = false;
#pragma unroll
    for (int r = 0; r < 4; ++r) upd |= (cm[r] > m_run[r]);
    if (__any(upd)) {
      float alpha[4];
#pragma unroll
      for (int r = 0; r < 4; ++r) {
        float mn = fmaxf(m_run[r], cm[r]);
        alpha[r] = __expf(m_run[r] - mn);
        m_run[r] = mn;
        l_run[r] *= alpha[r];
      }
#pragma unroll
      for (int t = 0; t < 16; ++t) {
#pragma unroll
        for (int r = 0; r < 4; ++r) oacc[t][r] *= alpha[r];
      }
    }

    float rs[4] = {0.f, 0.f, 0.f, 0.f};
    const int prow = wave * 16 + rgrp * 4;
#pragma unroll
    for (int t = 0; t < 4; ++t) {
#pragma unroll
      for (int r = 0; r < 4; ++r) {
        float p = __expf(s[t][r] - m_run[r]);
        rs[r] += p;
        lds[46080 + (prow + r) * 72 + t * 16 + col] = f2bf(p);
      }
    }
#pragma unroll
    for (int r = 0; r < 4; ++r) {
#pragma unroll
      for (int msk = 1; msk < 16; msk <<= 1) rs[r] += __shfl_xor(rs[r], msk);
      l_run[r] += rs[r];
    }

    // PV (pS is wave-private: no barrier between write and read)
    short8 ap[2];
#pragma unroll
    for (int ks = 0; ks < 2; ++ks)
      ap[ks] = *(const short8*)&lds[46080 + (wave * 16 + col) * 72 + ks * 32 + rgrp * 8];
#pragma unroll
    for (int t = 0; t < 16; ++t) {
#pragma unroll
      for (int ks = 0; ks < 2; ++ks) {
        short8 bh = *(const short8*)&lds[cur + 4608 + (t * 16 + col) * 72 + ks * 32 + rgrp * 8];
        oacc[t] = __builtin_amdgcn_mfma_f32_16x16x32_bf16(ap[ks], bh, oacc[t], 0, 0, 0);
      }
    }

    if (kc < 15) {  // write-late into the other buffer
      *(uint4*)&lds[nxt + fdst] = rf;
#pragma unroll
      for (int r = 0; r < 4; ++r) *(uint4*)&lds[nxt + hdst[r]] = rh[r];
    }
    __syncthreads();  // one barrier per chunk
  }

  // epilogue: normalize, assemble bf16 in LDS (alias @0; loop-end barrier protects)
  float inv[4];
#pragma unroll
  for (int r = 0; r < 4; ++r) inv[r] = 1.0f / l_run[r];
  const int qrow = wave * 16 + rgrp * 4;
#pragma unroll
  for (int t = 0; t < 16; ++t) {
#pragma unroll
    for (int r = 0; r < 4; ++r)
      lds[(qrow + r) * 264 + t * 16 + col] = f2bf(oacc[t][r] * inv[r]);
  }
  __syncthreads();
  unsigned short* Ob = O + ((size_t)b * NTOK + qt * 128) * 256;
#pragma unroll
  for (int r = 0; r < 8; ++r) {
    int idx = tid + r * 512;
    int q = idx >> 5, d8 = (idx & 31) << 3;
    *(uint4*)(Ob + (size_t)q * 256 + d8) = *(const uint4*)&lds[q * 264 + d8];
  }
}

// MFMA out-GEMM: out = gamma*(o @ wo) + x. A=o bf16 [32768][256], B=woT[512][256] bf16.
// v3 (round-5 form, unchanged): 512 threads / 8 waves, block tile 64 x 512.
__global__ __launch_bounds__(512) void gemm_out_mfma(const unsigned short* __restrict__ Obf,
                                                     const unsigned short* __restrict__ woT,
                                                     const float* __restrict__ Xres,
                                                     const float* __restrict__ gamma,
                                                     float* __restrict__ Out) {
  __shared__ unsigned short lds[23040];  // As[64][40] @0 ; WsT[512][40] @2560
  const int tid = threadIdx.x;
  const int bx = blockIdx.x;
  const int wave = tid >> 6, lane = tid & 63;
  const int col = lane & 15, rgrp = lane >> 4;
  const int wc = wave * 64;

  f32x4 acc[4][4];
#pragma unroll
  for (int mt = 0; mt < 4; ++mt)
#pragma unroll
    for (int nt = 0; nt < 4; ++nt) acc[mt][nt] = (f32x4){0.f, 0.f, 0.f, 0.f};

  for (int kt = 0; kt < 8; ++kt) {
    __syncthreads();
    if (tid < 256) {  // A: 64 rows x 32 k (256 uint4)
      int m = tid >> 2, k8 = (tid & 3) << 3;
      *(uint4*)&lds[m * 40 + k8] =
          *(const uint4*)(Obf + ((size_t)bx * 64 + m) * 256 + kt * 32 + k8);
    }
#pragma unroll
    for (int r = 0; r < 4; ++r) {  // B: 512 n x 32 k (2048 uint4, 4/thread)
      int idx = tid + r * 512;
      int n = idx >> 2, k8 = (idx & 3) << 3;
      *(uint4*)&lds[2560 + n * 40 + k8] =
          *(const uint4*)(woT + (size_t)n * 256 + kt * 32 + k8);
    }
    __syncthreads();

    short8 am[4];
#pragma unroll
    for (int mt = 0; mt < 4; ++mt)
      am[mt] = *(const short8*)&lds[(mt * 16 + col) * 40 + rgrp * 8];
#pragma unroll
    for (int nt = 0; nt < 4; ++nt) {
      short8 bn = *(const short8*)&lds[2560 + (wc + nt * 16 + col) * 40 + rgrp * 8];
#pragma unroll
      for (int mt = 0; mt < 4; ++mt)
        acc[mt][nt] = __builtin_amdgcn_mfma_f32_16x16x32_bf16(am[mt], bn, acc[mt][nt], 0, 0, 0);
    }
  }

  float gm = gamma[0];
#pragma unroll
  for (int mt = 0; mt < 4; ++mt) {
#pragma unroll
    for (int nt = 0; nt < 4; ++nt) {
      int n = wc + nt * 16 + col;
#pragma unroll
      for (int reg = 0; reg < 4; ++reg) {
        size_t row = (size_t)bx * 64 + mt * 16 + rgrp * 4 + reg;
        size_t off = row * 512 + n;
        Out[off] = gm * acc[mt][nt][reg] + Xres[off];
      }
    }
  }
}

extern "C" void kernel_launch(void* const* d_in, const int* in_sizes, int n_in,
                              void* d_out, int out_size, void* d_ws, size_t ws_size,
                              hipStream_t stream) {
  (void)in_sizes; (void)n_in; (void)out_size; (void)ws_size;
  const float* x     = (const float*)d_in[0];
  const float* wf    = (const float*)d_in[1];
  const float* wg    = (const float*)d_in[2];
  const float* wh    = (const float*)d_in[3];
  const float* wo    = (const float*)d_in[4];
  const float* gamma = (const float*)d_in[5];
  float* out = (float*)d_out;

  unsigned short* ws = (unsigned short*)d_ws;
  unsigned short* oB    = ws;               // [32768][256] bf16
  unsigned short* gB    = ws + 8388608;     // [32768][64]
  unsigned short* fB    = ws + 10485760;    // [8192][64]
  unsigned short* hT    = ws + 11010048;    // [8][256][1024]
  unsigned short* wcatT = ws + 13107200;    // [384][512]
  unsigned short* woT   = ws + 13303808;    // [512][256]

  pack_w<<<1280, dim3(256), 0, stream>>>(wf, wg, wh, wo, wcatT, woT);
  fgh_proj<<<512, dim3(512), 0, stream>>>(x, wcatT, fB, gB, hT);
  attn_mfma<<<256, dim3(512), 0, stream>>>((const __hip_bfloat16*)gB, (const __hip_bfloat16*)fB,
                                           (const __hip_bfloat16*)hT, oB);
  gemm_out_mfma<<<512, dim3(512), 0, stream>>>(oB, woT, x, gamma, out);
}

// Round 7
// 229.225 us; speedup vs baseline: 1.1090x; 1.1090x over previous
//
#include <hip/hip_runtime.h>
#include <hip/hip_bf16.h>

#define NTOK 4096   // 64*64 tokens per batch
#define NPOOL 1024  // 32*32 pooled tokens per batch

using short8 = __attribute__((ext_vector_type(8))) short;
using f32x4  = __attribute__((ext_vector_type(4))) float;

__device__ __forceinline__ unsigned short f2bf(float f) {
  __hip_bfloat16 h = __float2bfloat16(f);
  return __builtin_bit_cast(unsigned short, h);
}

// Map local tile row m (0..63) to a global x row such that rows 4*p..4*p+3 are
// the 2x2 pooling corners of pooled row bx*16+p.
__device__ __forceinline__ int pool_row(int bx, int m) {
  int pg = bx * 16 + (m >> 2);
  int corner = m & 3;
  int batch = pg >> 10;
  int pl = pg & 1023;
  int pi = pl >> 5, pj = pl & 31;
  return (batch << 12) + ((2 * pi + (corner >> 1)) << 6) + 2 * pj + (corner & 1);
}

// Pack weights: wcatT[384][512] = [f(64) | g(64) | h(256)]^T bf16; woT[512][256] bf16.
__global__ __launch_bounds__(256) void pack_w(const float* __restrict__ wf,
                                              const float* __restrict__ wg,
                                              const float* __restrict__ wh,
                                              const float* __restrict__ wo,
                                              unsigned short* __restrict__ wcatT,
                                              unsigned short* __restrict__ woT) {
  int i = blockIdx.x * 256 + threadIdx.x;
  if (i < 384 * 512) {
    int n = i >> 9, k = i & 511;
    float v = (n < 64) ? wf[k * 64 + n]
            : (n < 128) ? wg[k * 64 + (n - 64)]
                        : wh[k * 256 + (n - 128)];
    wcatT[i] = f2bf(v);
  } else if (i < 384 * 512 + 512 * 256) {
    int j = i - 384 * 512;
    int n = j >> 8, k = j & 255;
    woT[j] = f2bf(wo[(size_t)k * 512 + n]);
  }
}

// Fused f/g/h projection, MFMA.
// v5: stage the x-tile ONCE (64 rows x full K=512, bf16, pitch 520) -> one
// barrier total; k-loop reads B-fragments DIRECTLY from wcatT (384 KB,
// L2-resident, reused by all 512 blocks). Zero in-loop barriers/staging:
// the L2-fit rule — staging L2-resident data was pure overhead.
__global__ __launch_bounds__(512) void fgh_proj(const float* __restrict__ x,
                                                const unsigned short* __restrict__ wcatT,
                                                unsigned short* __restrict__ fB,
                                                unsigned short* __restrict__ gB,
                                                unsigned short* __restrict__ hT) {
  __shared__ unsigned short lds[33280];  // As[64][520] (66560 B); epilogue aliases @0
  const int tid = threadIdx.x;
  const int bx = blockIdx.x;
  const int wave = tid >> 6, lane = tid & 63;
  const int col = lane & 15, rgrp = lane >> 4;
  const int wcol = wave * 48;

  // stage x-tile once: row m = tid>>3, this thread covers float4 slot (tid&7) of each 32-k chunk
  {
    const int xm = tid >> 3, xk4 = (tid & 7) << 2;
    const float* xrow = x + (size_t)pool_row(bx, xm) * 512 + xk4;
    unsigned short* dst = &lds[xm * 520 + xk4];
#pragma unroll
    for (int kt = 0; kt < 16; ++kt) {
      float4 v = *(const float4*)(xrow + kt * 32);
      ushort4 o4;
      o4.x = f2bf(v.x); o4.y = f2bf(v.y); o4.z = f2bf(v.z); o4.w = f2bf(v.w);
      *(ushort4*)(dst + kt * 32) = o4;
    }
  }
  __syncthreads();  // the only staging barrier

  f32x4 acc[4][3];
#pragma unroll
  for (int mt = 0; mt < 4; ++mt)
#pragma unroll
    for (int nt = 0; nt < 3; ++nt) acc[mt][nt] = (f32x4){0.f, 0.f, 0.f, 0.f};

  for (int kt = 0; kt < 16; ++kt) {
    short8 am[4];
#pragma unroll
    for (int mt = 0; mt < 4; ++mt)
      am[mt] = *(const short8*)&lds[(mt * 16 + col) * 520 + kt * 32 + rgrp * 8];
#pragma unroll
    for (int nt = 0; nt < 3; ++nt) {
      short8 bn = *(const short8*)(wcatT + (size_t)(wcol + nt * 16 + col) * 512 + kt * 32 + rgrp * 8);
#pragma unroll
      for (int mt = 0; mt < 4; ++mt)
        acc[mt][nt] = __builtin_amdgcn_mfma_f32_16x16x32_bf16(am[mt], bn, acc[mt][nt], 0, 0, 0);
    }
  }
  __syncthreads();

  // epilogue assembly in LDS (alias over staging)
  unsigned short* gO = lds;          // [64][72]
  unsigned short* fO = lds + 4608;   // [16][72]
  unsigned short* hO = lds + 5760;   // [256][24]
#pragma unroll
  for (int mt = 0; mt < 4; ++mt) {
#pragma unroll
    for (int nt = 0; nt < 3; ++nt) {
      int n = wcol + nt * 16 + col;
      f32x4 a = acc[mt][nt];
      if (n < 64) {
        float mx = fmaxf(fmaxf(a[0], a[1]), fmaxf(a[2], a[3]));
        fO[(mt * 4 + rgrp) * 72 + n] = f2bf(mx);
      } else if (n < 128) {
#pragma unroll
        for (int reg = 0; reg < 4; ++reg)
          gO[(mt * 16 + rgrp * 4 + reg) * 72 + (n - 64)] = f2bf(a[reg]);
      } else {
        float mx = fmaxf(fmaxf(a[0], a[1]), fmaxf(a[2], a[3]));
        hO[(n - 128) * 24 + (mt * 4 + rgrp)] = f2bf(mx);
      }
    }
  }
  __syncthreads();

  const int b = bx >> 6, pkb = (bx & 63) * 16;
  {  // g: 64 rows x 64 ch (rows permuted), 512 uint4, 1/thread
    int m = tid >> 3, d8 = (tid & 7) << 3;
    *(uint4*)(gB + (size_t)pool_row(bx, m) * 64 + d8) = *(const uint4*)&gO[m * 72 + d8];
  }
  if (tid < 128) {  // f: 16 pooled rows x 64 ch
    int pr = tid >> 3, d8 = (tid & 7) << 3;
    *(uint4*)(fB + (size_t)(bx * 16 + pr) * 64 + d8) = *(const uint4*)&fO[pr * 72 + d8];
  }
  {  // hT: 256 dv x 16 pooled, 512 uint4, 1/thread
    int dv = tid >> 1, p8 = (tid & 1) << 3;
    *(uint4*)(hT + (((size_t)b * 256 + dv) << 10) + pkb + p8) = *(const uint4*)&hO[dv * 24 + p8];
  }
}

// MFMA flash attention; bf16 output o[32768][256].
// Round-5 WINNER form, unchanged: 8-wave block, 128 q-rows, 256 blocks (1/CU),
// single-buffer staging with 2 barriers/chunk. (R6's LDS double-buffer doubled
// bank conflicts and regressed — do not reintroduce.)
__global__ __launch_bounds__(512) void attn_mfma(const __hip_bfloat16* __restrict__ G,
                                                 const __hip_bfloat16* __restrict__ F,
                                                 const __hip_bfloat16* __restrict__ HT,
                                                 unsigned short* __restrict__ O) {
  // staging: fS[64][72] @0 ; hS[256][72] @4608 ; pS[128][72] @23040  (32256 ush)
  // epilogue alias: oS[128][264] @0 (33792 ush = 67584 B total)
  __shared__ unsigned short lds[33792];

  const int tid = threadIdx.x;
  const int wave = tid >> 6, lane = tid & 63;
  const int col = lane & 15;
  const int rgrp = lane >> 4;
  const int b = blockIdx.x >> 5, qt = blockIdx.x & 31;

  const unsigned short* Gb = (const unsigned short*)G + ((size_t)b * NTOK + qt * 128) * 64;
  const unsigned short* Fb = (const unsigned short*)F + (size_t)b * NPOOL * 64;
  const unsigned short* Hb = (const unsigned short*)HT + (size_t)b * 256 * NPOOL;

  // Q fragment straight from global (read once); wave w owns q-rows w*16..w*16+15
  short8 ag[2];
#pragma unroll
  for (int ks = 0; ks < 2; ++ks)
    ag[ks] = *(const short8*)(Gb + (size_t)(wave * 16 + col) * 64 + ks * 32 + rgrp * 8);

  f32x4 oacc[16];
#pragma unroll
  for (int t = 0; t < 16; ++t) oacc[t] = (f32x4){0.f, 0.f, 0.f, 0.f};
  float m_run[4], l_run[4];
#pragma unroll
  for (int r = 0; r < 4; ++r) { m_run[r] = -1e30f; l_run[r] = 0.f; }

  const int fk = tid >> 3, fd8 = (tid & 7) << 3;  // F staging (1 uint4/thread)

  for (int kc = 0; kc < 16; ++kc) {
    __syncthreads();  // previous chunk's LDS reads done
    // F chunk: 64 k-rows x 64 d
    *(uint4*)&lds[fk * 72 + fd8] =
        *(const uint4*)(Fb + (size_t)(kc * 64 + fk) * 64 + fd8);
    // H chunk: 256 dv-rows x 64 k
#pragma unroll
    for (int r = 0; r < 4; ++r) {
      int j = tid + r * 512;
      int dv = j >> 3, k8 = (j & 7) << 3;
      *(uint4*)&lds[4608 + dv * 72 + k8] =
          *(const uint4*)(Hb + (size_t)dv * NPOOL + kc * 64 + k8);
    }
    __syncthreads();  // data ready

    // QK^T
    f32x4 s[4];
#pragma unroll
    for (int t = 0; t < 4; ++t) s[t] = (f32x4){0.f, 0.f, 0.f, 0.f};
#pragma unroll
    for (int ks = 0; ks < 2; ++ks) {
#pragma unroll
      for (int t = 0; t < 4; ++t) {
        short8 bf = *(const short8*)&lds[(t * 16 + col) * 72 + ks * 32 + rgrp * 8];
        s[t] = __builtin_amdgcn_mfma_f32_16x16x32_bf16(ag[ks], bf, s[t], 0, 0, 0);
      }
    }

    // online softmax with exact defer-rescale
    float cm[4];
#pragma unroll
    for (int r = 0; r < 4; ++r) {
      cm[r] = fmaxf(fmaxf(s[0][r], s[1][r]), fmaxf(s[2][r], s[3][r]));
#pragma unroll
      for (int msk = 1; msk < 16; msk <<= 1) cm[r] = fmaxf(cm[r], __shfl_xor(cm[r], msk));
    }
    bool upd = false;
#pragma unroll
    for (int r = 0; r < 4; ++r) upd |= (cm[r] > m_run[r]);
    if (__any(upd)) {
      float alpha[4];
#pragma unroll
      for (int r = 0; r < 4; ++r) {
        float mn = fmaxf(m_run[r], cm[r]);
        alpha[r] = __expf(m_run[r] - mn);
        m_run[r] = mn;
        l_run[r] *= alpha[r];
      }
#pragma unroll
      for (int t = 0; t < 16; ++t) {
#pragma unroll
        for (int r = 0; r < 4; ++r) oacc[t][r] *= alpha[r];
      }
    }

    float rs[4] = {0.f, 0.f, 0.f, 0.f};
    const int prow = wave * 16 + rgrp * 4;
#pragma unroll
    for (int t = 0; t < 4; ++t) {
#pragma unroll
      for (int r = 0; r < 4; ++r) {
        float p = __expf(s[t][r] - m_run[r]);
        rs[r] += p;
        lds[23040 + (prow + r) * 72 + t * 16 + col] = f2bf(p);
      }
    }
#pragma unroll
    for (int r = 0; r < 4; ++r) {
#pragma unroll
      for (int msk = 1; msk < 16; msk <<= 1) rs[r] += __shfl_xor(rs[r], msk);
      l_run[r] += rs[r];
    }

    // PV (pS is wave-private)
    short8 ap[2];
#pragma unroll
    for (int ks = 0; ks < 2; ++ks)
      ap[ks] = *(const short8*)&lds[23040 + (wave * 16 + col) * 72 + ks * 32 + rgrp * 8];
#pragma unroll
    for (int t = 0; t < 16; ++t) {
#pragma unroll
      for (int ks = 0; ks < 2; ++ks) {
        short8 bh = *(const short8*)&lds[4608 + (t * 16 + col) * 72 + ks * 32 + rgrp * 8];
        oacc[t] = __builtin_amdgcn_mfma_f32_16x16x32_bf16(ap[ks], bh, oacc[t], 0, 0, 0);
      }
    }
  }

  // epilogue: normalize, assemble bf16 in LDS (alias), coalesced store
  float inv[4];
#pragma unroll
  for (int r = 0; r < 4; ++r) inv[r] = 1.0f / l_run[r];
  __syncthreads();
  const int qrow = wave * 16 + rgrp * 4;
#pragma unroll
  for (int t = 0; t < 16; ++t) {
#pragma unroll
    for (int r = 0; r < 4; ++r)
      lds[(qrow + r) * 264 + t * 16 + col] = f2bf(oacc[t][r] * inv[r]);
  }
  __syncthreads();
  unsigned short* Ob = O + ((size_t)b * NTOK + qt * 128) * 256;
#pragma unroll
  for (int r = 0; r < 8; ++r) {
    int idx = tid + r * 512;
    int q = idx >> 5, d8 = (idx & 31) << 3;
    *(uint4*)(Ob + (size_t)q * 256 + d8) = *(const uint4*)&lds[q * 264 + d8];
  }
}

// MFMA out-GEMM: out = gamma*(o @ wo) + x. A=o bf16 [32768][256], B=woT[512][256] bf16.
// v4: stage A ONCE (64x256 bf16, pitch 264) -> one barrier; k-loop reads
// B-fragments DIRECTLY from woT (256 KB, L2-resident). Zero in-loop barriers.
__global__ __launch_bounds__(512) void gemm_out_mfma(const unsigned short* __restrict__ Obf,
                                                     const unsigned short* __restrict__ woT,
                                                     const float* __restrict__ Xres,
                                                     const float* __restrict__ gamma,
                                                     float* __restrict__ Out) {
  __shared__ unsigned short lds[16896];  // As[64][264] (33792 B)
  const int tid = threadIdx.x;
  const int bx = blockIdx.x;
  const int wave = tid >> 6, lane = tid & 63;
  const int col = lane & 15, rgrp = lane >> 4;
  const int wc = wave * 64;

  // stage A once: 64 rows x 256 k = 2048 uint4, 4/thread
#pragma unroll
  for (int r = 0; r < 4; ++r) {
    int idx = tid + r * 512;
    int m = idx >> 5, k8 = (idx & 31) << 3;
    *(uint4*)&lds[m * 264 + k8] =
        *(const uint4*)(Obf + ((size_t)bx * 64 + m) * 256 + k8);
  }
  __syncthreads();  // the only barrier

  f32x4 acc[4][4];
#pragma unroll
  for (int mt = 0; mt < 4; ++mt)
#pragma unroll
    for (int nt = 0; nt < 4; ++nt) acc[mt][nt] = (f32x4){0.f, 0.f, 0.f, 0.f};

  for (int kt = 0; kt < 8; ++kt) {
    short8 am[4];
#pragma unroll
    for (int mt = 0; mt < 4; ++mt)
      am[mt] = *(const short8*)&lds[(mt * 16 + col) * 264 + kt * 32 + rgrp * 8];
#pragma unroll
    for (int nt = 0; nt < 4; ++nt) {
      short8 bn = *(const short8*)(woT + (size_t)(wc + nt * 16 + col) * 256 + kt * 32 + rgrp * 8);
#pragma unroll
      for (int mt = 0; mt < 4; ++mt)
        acc[mt][nt] = __builtin_amdgcn_mfma_f32_16x16x32_bf16(am[mt], bn, acc[mt][nt], 0, 0, 0);
    }
  }

  float gm = gamma[0];
#pragma unroll
  for (int mt = 0; mt < 4; ++mt) {
#pragma unroll
    for (int nt = 0; nt < 4; ++nt) {
      int n = wc + nt * 16 + col;
#pragma unroll
      for (int reg = 0; reg < 4; ++reg) {
        size_t row = (size_t)bx * 64 + mt * 16 + rgrp * 4 + reg;
        size_t off = row * 512 + n;
        Out[off] = gm * acc[mt][nt][reg] + Xres[off];
      }
    }
  }
}

extern "C" void kernel_launch(void* const* d_in, const int* in_sizes, int n_in,
                              void* d_out, int out_size, void* d_ws, size_t ws_size,
                              hipStream_t stream) {
  (void)in_sizes; (void)n_in; (void)out_size; (void)ws_size;
  const float* x     = (const float*)d_in[0];
  const float* wf    = (const float*)d_in[1];
  const float* wg    = (const float*)d_in[2];
  const float* wh    = (const float*)d_in[3];
  const float* wo    = (const float*)d_in[4];
  const float* gamma = (const float*)d_in[5];
  float* out = (float*)d_out;

  unsigned short* ws = (unsigned short*)d_ws;
  unsigned short* oB    = ws;               // [32768][256] bf16
  unsigned short* gB    = ws + 8388608;     // [32768][64]
  unsigned short* fB    = ws + 10485760;    // [8192][64]
  unsigned short* hT    = ws + 11010048;    // [8][256][1024]
  unsigned short* wcatT = ws + 13107200;    // [384][512]
  unsigned short* woT   = ws + 13303808;    // [512][256]

  pack_w<<<1280, dim3(256), 0, stream>>>(wf, wg, wh, wo, wcatT, woT);
  fgh_proj<<<512, dim3(512), 0, stream>>>(x, wcatT, fB, gB, hT);
  attn_mfma<<<256, dim3(512), 0, stream>>>((const __hip_bfloat16*)gB, (const __hip_bfloat16*)fB,
                                           (const __hip_bfloat16*)hT, oB);
  gemm_out_mfma<<<512, dim3(512), 0, stream>>>(oB, woT, x, gamma, out);
}